// Round 3
// baseline (163.690 us; speedup 1.0000x reference)
//
#include <hip/hip_runtime.h>
#include <hip/hip_bf16.h>
#include <hip/hip_fp16.h>
#include <stdint.h>

#define LOSS_IDX 8388608
#define IDX_BASE 8388609

typedef _Float16 half8 __attribute__((ext_vector_type(8)));
typedef float f32x4 __attribute__((ext_vector_type(4)));
typedef unsigned long long u64;

// ---- workspace layout (bytes) ----
#define WIN_OFF  0          // 32768 * 8   winner (key<<32 | k)
#define E2_OFF   262144     // 1024 * 4    code norms
#define EIMG_OFF 266240     // 1 MiB       frag-linear fp16 hi/lo emb image
// z-image (33.55 MB) lives in d_out[0..8388608) — exact fit; k3 overwrites.
//
// frag-linear image (16x16x32 MFMA A/B layout, verified m120/m89):
//   elem (row r, c): g=r>>4, m=r&15, cc=c>>5, quad=(c>>3)&3, j=c&7
//   ushort idx = (((g*8+cc)*2+pl)*64 + m + 16*quad)*8 + j
//   -> each (g,cc) is a contiguous 2048B block [pl][lane][j]: DMA-able,
//      and a frag read is lane*16B contiguous (max-BW LDS pattern).

static __device__ __forceinline__ unsigned fkey(float d) {
    unsigned u = __float_as_uint(d);
    return u ^ ((unsigned)(((int)u) >> 31) | 0x80000000u);
}

// ---------------------------------------------------------------------------
// K0: emb -> e-image (frag-linear hi/lo), e2 norms, win init, loss=0.
// 128 blocks x 256 thr; thread = (code, oct o): 8 c's.
// ---------------------------------------------------------------------------
__global__ __launch_bounds__(256) void k0_prep(
    const float* __restrict__ emb, float* __restrict__ e2,
    ushort* __restrict__ eimg, u64* __restrict__ win64,
    float* __restrict__ out) {
    int tid = blockIdx.x * 256 + threadIdx.x;      // 0..32767
    win64[tid] = ~0ull;
    if (tid == 0) out[LOSS_IDX] = 0.f;
    int code = tid >> 5, o = tid & 31;
    const float4 v0 = *(const float4*)&emb[code * 256 + o * 8];
    const float4 v1 = *(const float4*)&emb[code * 256 + o * 8 + 4];
    float v[8] = {v0.x, v0.y, v0.z, v0.w, v1.x, v1.y, v1.z, v1.w};
    float s = 0.f;
    half8 hi, lo;
    #pragma unroll
    for (int j = 0; j < 8; ++j) {
        s = fmaf(v[j], v[j], s);
        __half h = __float2half(v[j]);
        __half l = __float2half(v[j] - __half2float(h));
        hi[j] = *(_Float16*)&h;
        lo[j] = *(_Float16*)&l;
    }
    int g = code >> 4, m = code & 15, cc = o >> 2, quad = o & 3;
    int base = (((g * 8 + cc) * 2 + 0) * 64 + m + 16 * quad) * 8;
    *(half8*)&eimg[base] = hi;
    *(half8*)&eimg[base + 512] = lo;   // pl=1 plane (+64*8)
    #pragma unroll
    for (int msk = 1; msk <= 16; msk <<= 1) s += __shfl_xor(s, msk, 64);
    if (o == 0) e2[code] = s;
}

// ---------------------------------------------------------------------------
// K1: z_e -> frag-linear hi/lo z-image (into d_out!) + sum(z^2) loss part 1.
// 512 blocks x 256 thr; block = 64 q; thread = (q, og): 8 octs = 64 c's.
// ---------------------------------------------------------------------------
__global__ __launch_bounds__(256) void k1_zimg(
    const float* __restrict__ z_e, ushort* __restrict__ zimg,
    float* __restrict__ out) {
    __shared__ float red[4];
    int t = threadIdx.x;
    int qbase = blockIdx.x * 64;
    int b = qbase >> 10, hw0 = qbase & 1023;
    int q = qbase + (t & 63);
    int og = t >> 6;
    const float* zb = z_e + b * (256 * 1024) + hw0 + (t & 63);
    int g = q >> 4, m = q & 15;
    float z2 = 0.f;
    #pragma unroll
    for (int oi = 0; oi < 8; ++oi) {
        int o = og * 8 + oi;
        float v[8];
        #pragma unroll
        for (int j = 0; j < 8; ++j) v[j] = zb[(o * 8 + j) * 1024];
        half8 hi, lo;
        #pragma unroll
        for (int j = 0; j < 8; ++j) {
            z2 = fmaf(v[j], v[j], z2);
            __half h = __float2half(v[j]);
            __half l = __float2half(v[j] - __half2float(h));
            hi[j] = *(_Float16*)&h;
            lo[j] = *(_Float16*)&l;
        }
        int base = (((g * 8 + (o >> 2)) * 2 + 0) * 64 + m + 16 * (o & 3)) * 8;
        *(half8*)&zimg[base] = hi;
        *(half8*)&zimg[base + 512] = lo;
    }
    #pragma unroll
    for (int off = 32; off > 0; off >>= 1) z2 += __shfl_down(z2, off, 64);
    if ((t & 63) == 0) red[og] = z2;   // og == wave id here
    __syncthreads();
    if (t == 0) {
        float s = red[0] + red[1] + red[2] + red[3];
        atomicAdd(&out[LOSS_IDX], s * (1.25f / 8388608.f));
    }
}

// ---------------------------------------------------------------------------
// K2: pure MFMA distance GEMM + argmin. 1024 blocks x 256 thr (4 waves).
// Block tile 128q x 256k; wave tile 64q x 128k (mt4 x nt8 of 16x16).
// Per cc: DMA A(16KB)+B(32KB) frag-linear; 24 ds_read_b128; 96 MFMA.
// ---------------------------------------------------------------------------
__global__ __launch_bounds__(256, 2) void k2_mfma(
    const ushort* __restrict__ zimg, const ushort* __restrict__ eimg,
    const float* __restrict__ e2g, u64* __restrict__ win64) {
    __shared__ __attribute__((aligned(16))) ushort as_[8192];   // 16 KB
    __shared__ __attribute__((aligned(16))) ushort bs_[16384];  // 32 KB
    int t = threadIdx.x;
    int lane = t & 63, w = t >> 6;
    int bid = blockIdx.x;
    int qg = ((bid >> 5) << 3) | (bid & 7);   // same-qg blocks -> same XCD
    int cg = (bid >> 3) & 3;
    int qh = w >> 1, nh = w & 1;

    f32x4 acc[4][8];
    #pragma unroll
    for (int mt = 0; mt < 4; ++mt)
        #pragma unroll
        for (int nt = 0; nt < 8; ++nt) acc[mt][nt] = (f32x4){0.f, 0.f, 0.f, 0.f};

    for (int cc = 0; cc < 8; ++cc) {
        __syncthreads();
        // DMA A chunk: 8 g-groups x 2048 B
        #pragma unroll
        for (int i = 0; i < 4; ++i) {
            int u = i * 256 + t;
            int gl = u >> 7, inner = u & 127;
            const char* src = (const char*)zimg +
                (size_t)((qg * 8 + gl) * 8 + cc) * 2048 + inner * 16;
            __builtin_amdgcn_global_load_lds(
                (const __attribute__((address_space(1))) unsigned int*)src,
                (__attribute__((address_space(3))) unsigned int*)((char*)as_ + u * 16),
                16, 0, 0);
        }
        // DMA B chunk: 16 ng-groups x 2048 B
        #pragma unroll
        for (int i = 0; i < 8; ++i) {
            int u = i * 256 + t;
            int ngl = u >> 7, inner = u & 127;
            const char* src = (const char*)eimg +
                (size_t)((cg * 16 + ngl) * 8 + cc) * 2048 + inner * 16;
            __builtin_amdgcn_global_load_lds(
                (const __attribute__((address_space(1))) unsigned int*)src,
                (__attribute__((address_space(3))) unsigned int*)((char*)bs_ + u * 16),
                16, 0, 0);
        }
        __syncthreads();
        half8 ah[4], al[4];
        #pragma unroll
        for (int mt = 0; mt < 4; ++mt) {
            int gl = qh * 4 + mt;
            ah[mt] = *(const half8*)&as_[(gl * 128 + lane) * 8];
            al[mt] = *(const half8*)&as_[(gl * 128 + 64 + lane) * 8];
        }
        #pragma unroll
        for (int nt = 0; nt < 8; ++nt) {
            int ngl = nh * 8 + nt;
            half8 bh = *(const half8*)&bs_[(ngl * 128 + lane) * 8];
            half8 bl = *(const half8*)&bs_[(ngl * 128 + 64 + lane) * 8];
            #pragma unroll
            for (int mt = 0; mt < 4; ++mt)
                acc[mt][nt] = __builtin_amdgcn_mfma_f32_16x16x32_f16(ah[mt], bh, acc[mt][nt], 0, 0, 0);
            #pragma unroll
            for (int mt = 0; mt < 4; ++mt)
                acc[mt][nt] = __builtin_amdgcn_mfma_f32_16x16x32_f16(ah[mt], bl, acc[mt][nt], 0, 0, 0);
            #pragma unroll
            for (int mt = 0; mt < 4; ++mt)
                acc[mt][nt] = __builtin_amdgcn_mfma_f32_16x16x32_f16(al[mt], bh, acc[mt][nt], 0, 0, 0);
        }
    }

    // argmin epilogue (verified C layout: col=lane&15, row=(lane>>4)*4+reg)
    int lm = lane & 15, lg = lane >> 4;
    int qbase = qg * 128;
    float e2v[8];
    #pragma unroll
    for (int nt = 0; nt < 8; ++nt)
        e2v[nt] = e2g[cg * 256 + nh * 128 + nt * 16 + lm];
    #pragma unroll
    for (int mt = 0; mt < 4; ++mt)
        #pragma unroll
        for (int r = 0; r < 4; ++r) {
            u64 best = ~0ull;
            #pragma unroll
            for (int nt = 0; nt < 8; ++nt) {
                float d = fmaf(-2.f, acc[mt][nt][r], e2v[nt]);
                u64 p = ((u64)fkey(d) << 32) |
                        (unsigned)(cg * 256 + nh * 128 + nt * 16 + lm);
                if (p < best) best = p;
            }
            #pragma unroll
            for (int msk = 1; msk <= 8; msk <<= 1) {   // reduce over 16 lm lanes
                unsigned blo = __shfl_xor((unsigned)best, msk, 64);
                unsigned bhi = __shfl_xor((unsigned)(best >> 32), msk, 64);
                u64 p = ((u64)bhi << 32) | blo;
                if (p < best) best = p;
            }
            if (lm == 0)
                atomicMin(&win64[qbase + qh * 64 + mt * 16 + lg * 4 + r], best);
        }
}

// ---------------------------------------------------------------------------
// K3: res = emb[k*] scattered to (b,c,h,w); indices as float; loss part 2
// from winner key (d'win = e2 - 2 z.e = (zq-z)^2 - z^2). Overwrites z-image.
// ---------------------------------------------------------------------------
__global__ __launch_bounds__(256, 2) void k3_out(
    const float* __restrict__ emb, const u64* __restrict__ win64,
    float* __restrict__ out) {
    __shared__ float lde[64 * 257];
    __shared__ int lwin[64];
    int t = threadIdx.x;
    int qbase = blockIdx.x * 64;
    int b = qbase >> 10;
    int hw0 = qbase & 1023;
    if (t < 64) {
        u64 p = win64[qbase + t];
        int k = (int)(p & 0xFFFFFFFFull);
        lwin[t] = k;
        out[IDX_BASE + qbase + t] = (float)k;
        unsigned key = (unsigned)(p >> 32);
        unsigned u = (key & 0x80000000u) ? (key ^ 0x80000000u) : ~key;
        float dval = __uint_as_float(u);
        #pragma unroll
        for (int off = 32; off > 0; off >>= 1) dval += __shfl_down(dval, off, 64);
        if (t == 0) atomicAdd(&out[LOSS_IDX], dval * (1.25f / 8388608.f));
    }
    __syncthreads();
    for (int i = 0; i < 64; ++i)
        lde[i * 257 + t] = emb[lwin[i] * 256 + t];
    __syncthreads();
    float* rb = out + b * (256 * 1024) + hw0;
    int j = t & 63, chi = t >> 6;
    #pragma unroll 4
    for (int p = 0; p < 64; ++p) {
        int c = p * 4 + chi;
        rb[c * 1024 + j] = lde[j * 257 + c];
    }
}

// ---------------------------------------------------------------------------
extern "C" void kernel_launch(void* const* d_in, const int* in_sizes, int n_in,
                              void* d_out, int out_size, void* d_ws, size_t ws_size,
                              hipStream_t stream) {
    const float* z_e = (const float*)d_in[0];   // (32,256,32,32) fp32
    const float* emb = (const float*)d_in[1];   // (1024,256) fp32
    float* out = (float*)d_out;
    u64*    win  = (u64*)((char*)d_ws + WIN_OFF);
    float*  e2   = (float*)((char*)d_ws + E2_OFF);
    ushort* eimg = (ushort*)((char*)d_ws + EIMG_OFF);
    ushort* zimg = (ushort*)d_out;              // scratch until k3 overwrites

    k0_prep<<<128, 256, 0, stream>>>(emb, e2, eimg, win, out);
    k1_zimg<<<512, 256, 0, stream>>>(z_e, zimg, out);
    k2_mfma<<<1024, 256, 0, stream>>>(zimg, eimg, e2, win);
    k3_out <<<512, 256, 0, stream>>>(emb, win, out);
}